// Round 8
// baseline (15963.120 us; speedup 1.0000x reference)
//
#include <hip/hip_runtime.h>

// GRU 2-layer persistent-kernel design (Round 9): SINGLE-XCD execution.
// B=64, S=1024, I=256, H=512, O=512.
// All 64 worker blocks placed on ONE XCD (XCC_ID==0): 32 CUs x 2 blocks/CU
// (LDS 2x70144 <= 160KB). Within an XCD the shared L2 IS the coherence point:
//   * h publish: PLAIN u16 stores (L1 is write-through -> L2 after vmcnt
//     drain at __syncthreads). No wbl2 ever. Dirty h lines live in XCD0 L2.
//   * h reads: PLAIN cached loads; correctness via per-CU L1-ONLY invalidate
//     (`buffer_inv`, ~50cy, parallel across CUs) at barrier exit. NO L2 inv,
//     NO L3 data path, NO 8-per-XCD serializing maintenance ops.
//   * barrier: R7's PROVEN sc1 store/poll (64B-stride slots, s_sleep(2)),
//     indexed by worker id; exit fence = buffer_inv + vmcnt(0) only.
// Worker claim: grid=1024 blocks; tid0 reads HW_REG_XCC_ID (m09-verified
// 0..7); XCD0 blocks take a device-atomic ticket; tickets 0..63 = workers
// (ticket = virtual blockIdx vb); all others exit. Late joiners are safe:
// barrier is monotonic, skew <= 1 interval, h ping-pong depth 2.
// __launch_bounds__(256,2) caps VGPR<=256 so 2 blocks/CU is guaranteed
// (LDS-bound). ybf/outh: plain stores (dirty L2, flushed at kernel end).

typedef unsigned short u16;
typedef unsigned long long u64;
typedef __attribute__((ext_vector_type(8))) short bf16x8;
typedef __attribute__((ext_vector_type(4))) float f32x4;

#define B_ 64
#define S_ 1024
#define I_ 256
#define H_ 512
#define O_ 512

#define MFMA_(a, b, c) __builtin_amdgcn_mfma_f32_16x16x32_bf16((a), (b), (c), 0, 0, 0)

__device__ __forceinline__ u16 f2bf(float f) {
  union { float f; unsigned u; } v; v.f = f;
  unsigned r = v.u + 0x7fffu + ((v.u >> 16) & 1u);  // RNE
  return (u16)(r >> 16);
}

__device__ __forceinline__ float sigmoidf_(float x) {
  return 1.0f / (1.0f + __expf(-x));
}

// Grid barrier (R9): R7's proven sc1 arrival/poll; L1-only inv on exit.
// slots: 64 entries, 64B stride; slot[vb] = last target worker vb reached.
// __syncthreads drains vmcnt(0): all plain h stores are ACKed into XCD0 L2
// before the arrival store issues -> poller sees slot => h is in L2.
__device__ __forceinline__ void grid_bar(unsigned* slots, int vb, unsigned target) {
  __syncthreads();
  if (threadIdx.x < 64) {
    if (threadIdx.x == 0) {
      __hip_atomic_store(slots + ((unsigned)vb << 4), target,
                         __ATOMIC_RELAXED, __HIP_MEMORY_SCOPE_AGENT);
    }
    const unsigned* myslot = slots + ((unsigned)threadIdx.x << 4);
    unsigned v;
    do {
      v = __hip_atomic_load(myslot, __ATOMIC_RELAXED, __HIP_MEMORY_SCOPE_AGENT);
      if (v < target) __builtin_amdgcn_s_sleep(2);
    } while (v < target);
    if (threadIdx.x == 0) {
      asm volatile("buffer_inv" ::: "memory");           // L1-only invalidate
      asm volatile("s_waitcnt vmcnt(0)" ::: "memory");   // inv complete
    }
  }
  __syncthreads();  // other waves held until L1 is clean
}

// One layer's persistent loop. NK = K/(32*4) per wave. LAYER selects routing.
// xin: LAYER0 -> x_bf [t][b][c]; LAYER1 -> h0 ping-pong base.
template<int NK, int LAYER>
__device__ void layer_run(
    const u16* __restrict__ xin,
    const float* __restrict__ Wih, const float* __restrict__ Whh,
    const float* __restrict__ bih, const float* __restrict__ bhh,
    u16* __restrict__ hself,            // ping-pong [2][64*512] bf16
    u16* __restrict__ ybf,              // LAYER1: [b][t][u] bf16
    float* __restrict__ outh,           // final hidden f32 [64*512]
    float (*dump)[4][4][256], float* hst, float (*bias_s)[16],
    unsigned* slots, int vb)
{
  const int tid = threadIdx.x;
  const int wave = tid >> 6, lane = tid & 63, lm = lane & 15, quad = lane >> 4;
  const int U0 = (vb & 31) << 4;               // this worker's 16 hidden units
  const int Kx = (LAYER == 0) ? I_ : H_;       // boundary between gi and gh input
  const int KW = NK * 32;                      // K-slice per wave
  const int wbase = wave * KW;

  if (tid < 16) {
    bias_s[0][tid] = bih[U0 + tid] + bhh[U0 + tid];                  // r
    bias_s[1][tid] = bih[H_ + U0 + tid] + bhh[H_ + U0 + tid];        // z
    bias_s[2][tid] = bih[2 * H_ + U0 + tid];                         // n (x part)
    bias_s[3][tid] = bhh[2 * H_ + U0 + tid];                         // n (h part)
  }
  #pragma unroll
  for (int j = 0; j < 4; ++j) hst[tid + j * 256] = 0.f;

  // ---- load B fragments once: f32 weights -> bf16 regs ----
  bf16x8 Bfr[3][NK];
  int aoffb[NK], astr16[NK];
  bool insel[NK], isx[NK];
  #pragma unroll
  for (int ks = 0; ks < NK; ++ks) {
    const int kb = wbase + ks * 32;
    const bool xr = (kb < Kx);
    insel[ks] = xr; isx[ks] = xr;
    const int col = (xr ? kb : kb - Kx) + quad * 8;
    const int stride = xr ? ((LAYER == 0) ? I_ : H_) : H_;
    aoffb[ks] = lm * stride + col;
    astr16[ks] = stride << 4;
    #pragma unroll
    for (int g = 0; g < 3; ++g) {
      const int row = g * H_ + U0 + lm;
      const float* src = xr ? (Wih + (size_t)row * Kx + kb + quad * 8)
                            : (Whh + (size_t)row * H_ + (kb - Kx) + quad * 8);
      float4 lo = *(const float4*)src;
      float4 hi = *(const float4*)(src + 4);
      bf16x8 v;
      v[0] = (short)f2bf(lo.x); v[1] = (short)f2bf(lo.y);
      v[2] = (short)f2bf(lo.z); v[3] = (short)f2bf(lo.w);
      v[4] = (short)f2bf(hi.x); v[5] = (short)f2bf(hi.y);
      v[6] = (short)f2bf(hi.z); v[7] = (short)f2bf(hi.w);
      Bfr[g][ks] = v;
    }
  }
  __syncthreads();

  // ---- time loop: 1025 barrier intervals ----
  for (unsigned i = 0; i <= S_; ++i) {
    const bool active = (LAYER == 0) ? (i < S_) : (i >= 1);
    if (active) {
      const int t = (LAYER == 0) ? (int)i : (int)i - 1;
      const u16* ain = (LAYER == 0) ? (xin + (size_t)t * (B_ * I_))
                                    : (xin + (size_t)(t & 1) * (B_ * H_));
      const u16* aself = hself + (size_t)((t - 1) & 1) * (B_ * H_);

      // ---- PHASE 1: issue ALL A-fragment loads (plain cached; L2-local) ----
      bf16x8 Afr[NK][4];
      #pragma unroll
      for (int ks = 0; ks < NK; ++ks) {
        const u16* p = (insel[ks] ? ain : aself) + aoffb[ks];
        Afr[ks][0] = *(const bf16x8*)(p);
        Afr[ks][1] = *(const bf16x8*)(p + astr16[ks]);
        Afr[ks][2] = *(const bf16x8*)(p + 2 * astr16[ks]);
        Afr[ks][3] = *(const bf16x8*)(p + 3 * astr16[ks]);
      }

      // ---- PHASE 2: all MFMAs (register-only) ----
      f32x4 aR[4] = {}, aZ[4] = {}, aNx[4] = {}, aNh[4] = {};
      #pragma unroll
      for (int ks = 0; ks < NK; ++ks) {
        aR[0] = MFMA_(Afr[ks][0], Bfr[0][ks], aR[0]);
        aR[1] = MFMA_(Afr[ks][1], Bfr[0][ks], aR[1]);
        aR[2] = MFMA_(Afr[ks][2], Bfr[0][ks], aR[2]);
        aR[3] = MFMA_(Afr[ks][3], Bfr[0][ks], aR[3]);
        aZ[0] = MFMA_(Afr[ks][0], Bfr[1][ks], aZ[0]);
        aZ[1] = MFMA_(Afr[ks][1], Bfr[1][ks], aZ[1]);
        aZ[2] = MFMA_(Afr[ks][2], Bfr[1][ks], aZ[2]);
        aZ[3] = MFMA_(Afr[ks][3], Bfr[1][ks], aZ[3]);
        if (isx[ks]) {
          aNx[0] = MFMA_(Afr[ks][0], Bfr[2][ks], aNx[0]);
          aNx[1] = MFMA_(Afr[ks][1], Bfr[2][ks], aNx[1]);
          aNx[2] = MFMA_(Afr[ks][2], Bfr[2][ks], aNx[2]);
          aNx[3] = MFMA_(Afr[ks][3], Bfr[2][ks], aNx[3]);
        } else {
          aNh[0] = MFMA_(Afr[ks][0], Bfr[2][ks], aNh[0]);
          aNh[1] = MFMA_(Afr[ks][1], Bfr[2][ks], aNh[1]);
          aNh[2] = MFMA_(Afr[ks][2], Bfr[2][ks], aNh[2]);
          aNh[3] = MFMA_(Afr[ks][3], Bfr[2][ks], aNh[3]);
        }
      }

      // dump partials to LDS
      #pragma unroll
      for (int mt = 0; mt < 4; ++mt) {
        *(f32x4*)&dump[wave][0][mt][lane << 2] = aR[mt];
        *(f32x4*)&dump[wave][1][mt][lane << 2] = aZ[mt];
        *(f32x4*)&dump[wave][2][mt][lane << 2] = aNx[mt];
        *(f32x4*)&dump[wave][3][mt][lane << 2] = aNh[mt];
      }
      __syncthreads();

      // reduce + gate math + publish (R3 conflict-free mapping; PLAIN stores
      // -> write-through L1 -> XCD0 L2, where all consumers read).
      u16* hpub = hself + (size_t)(t & 1) * (B_ * H_);
      #pragma unroll
      for (int j = 0; j < 4; ++j) {
        const int v = tid + (j << 8);
        const int m = v >> 4, u = v & 15;
        const int mt = m >> 4;
        const int ln = ((m & 12) << 2) | u;    // quad(m)*16 + u
        const int idx = (ln << 2) | (m & 3);
        float r = 0.f, z = 0.f, nx = 0.f, nh = 0.f;
        #pragma unroll
        for (int w = 0; w < 4; ++w) {
          r  += dump[w][0][mt][idx];
          z  += dump[w][1][mt][idx];
          nx += dump[w][2][mt][idx];
          nh += dump[w][3][mt][idx];
        }
        r = sigmoidf_(r + bias_s[0][u]);
        z = sigmoidf_(z + bias_s[1][u]);
        const float nn = tanhf(nx + bias_s[2][u] + r * (nh + bias_s[3][u]));
        const float hp = hst[(m << 4) | u];
        const float hn = (1.f - z) * nn + z * hp;
        hst[(m << 4) | u] = hn;
        const u16 hb = f2bf(hn);
        hpub[m * H_ + U0 + u] = hb;
        if (LAYER == 1) ybf[((size_t)m * S_ + t) * H_ + U0 + u] = hb;
        if (t == S_ - 1) outh[m * H_ + U0 + u] = hn;
      }
    }
    grid_bar(slots, vb, i + 1);
  }
}

__global__ __launch_bounds__(256, 2) void gru_persistent(
    const u16* __restrict__ x_bf,
    const float* __restrict__ Wih0, const float* __restrict__ Whh0,
    const float* __restrict__ bih0, const float* __restrict__ bhh0,
    const float* __restrict__ Wih1, const float* __restrict__ Whh1,
    const float* __restrict__ bih1, const float* __restrict__ bhh1,
    u16* __restrict__ h0buf, u16* __restrict__ h1buf,
    u16* __restrict__ ybf, float* __restrict__ outh,
    unsigned* slots, int* ticket)
{
  __shared__ float dump[4][4][4][256];   // 64 KB
  __shared__ float hst[1024];            // 4 KB fp32 h state (this block's slice)
  __shared__ float bias_s[4][16];
  __shared__ int vb_s;

  // ---- worker claim: only blocks on XCD 0; first 64 tickets win ----
  if (threadIdx.x == 0) {
    unsigned xcc;
    asm volatile("s_getreg_b32 %0, hwreg(HW_REG_XCC_ID)" : "=s"(xcc));
    int v = -1;
    if (xcc == 0) v = atomicAdd(ticket, 1);   // device-scope
    vb_s = v;
  }
  __syncthreads();
  const int vb = vb_s;
  if (vb < 0 || vb >= 64) return;             // non-worker: exit, free the CU

  if (vb < 32)
    layer_run<6, 0>(x_bf, Wih0, Whh0, bih0, bhh0, h0buf, (u16*)nullptr,
                    outh, dump, hst, bias_s, slots, vb);
  else
    layer_run<8, 1>(h0buf, Wih1, Whh1, bih1, bhh1, h1buf, ybf,
                    outh + B_ * H_, dump, hst, bias_s, slots, vb);
}

// ---------------- x transpose+convert: [b][t][c] f32 -> [t][b][c] bf16 ----------------
__global__ void conv_x(const float* __restrict__ src, u16* __restrict__ dst) {
  const int idx = blockIdx.x * 256 + threadIdx.x;   // 64*1024*64 quads
  const int c4 = idx & 63, tt = (idx >> 6) & 1023, b = idx >> 16;
  float4 v = *(const float4*)(src + (((size_t)(b << 10) | tt) << 8) + (c4 << 2));
  ushort4 o;
  o.x = f2bf(v.x); o.y = f2bf(v.y); o.z = f2bf(v.z); o.w = f2bf(v.w);
  *(ushort4*)(dst + (((size_t)(tt << 6) | b) << 8) + (c4 << 2)) = o;
}

// ---------------- generic f32 -> bf16 ----------------
__global__ void conv_bf16(const float* __restrict__ src, u16* __restrict__ dst, int n4) {
  int i = blockIdx.x * blockDim.x + threadIdx.x;
  int stride = gridDim.x * blockDim.x;
  for (; i < n4; i += stride) {
    float4 v = ((const float4*)src)[i];
    ushort4 o;
    o.x = f2bf(v.x); o.y = f2bf(v.y); o.z = f2bf(v.z); o.w = f2bf(v.w);
    ((ushort4*)dst)[i] = o;
  }
}

// ---------------- final FC: C[65536,512] = Y @ Wfc^T + b (verified R1) ----------------
__global__ __launch_bounds__(256) void fc_gemm(
    const u16* __restrict__ A, const u16* __restrict__ Bm,
    const float* __restrict__ bias, float* __restrict__ C)
{
  const int bid = blockIdx.x;
  const int bm = bid >> 2, bn = bid & 3;
  const int wave = threadIdx.x >> 6, lane = threadIdx.x & 63;
  const int wm = wave >> 1, wn = wave & 1;
  const int M0 = bm * 128 + wm * 64;
  const int N0 = bn * 128 + wn * 64;
  const int lm = lane & 15, quad = lane >> 4;

  f32x4 acc[4][4];
  #pragma unroll
  for (int j = 0; j < 4; ++j) {
    float bv = bias[N0 + j * 16 + lm];
    #pragma unroll
    for (int i = 0; i < 4; ++i) acc[i][j] = (f32x4){bv, bv, bv, bv};
  }

  const u16* a0 = A + (size_t)(M0 + lm) * 512 + quad * 8;
  const u16* b0 = Bm + (size_t)(N0 + lm) * 512 + quad * 8;
  for (int ks = 0; ks < 512; ks += 32) {
    bf16x8 af[4], bfr[4];
    #pragma unroll
    for (int i = 0; i < 4; ++i) af[i]  = *(const bf16x8*)(a0 + (size_t)i * 16 * 512 + ks);
    #pragma unroll
    for (int j = 0; j < 4; ++j) bfr[j] = *(const bf16x8*)(b0 + (size_t)j * 16 * 512 + ks);
    #pragma unroll
    for (int i = 0; i < 4; ++i)
      #pragma unroll
      for (int j = 0; j < 4; ++j)
        acc[i][j] = MFMA_(af[i], bfr[j], acc[i][j]);
  }

  #pragma unroll
  for (int i = 0; i < 4; ++i)
    #pragma unroll
    for (int j = 0; j < 4; ++j)
      #pragma unroll
      for (int r = 0; r < 4; ++r) {
        const int m = M0 + i * 16 + quad * 4 + r;
        const int n = N0 + j * 16 + lm;
        C[(size_t)m * 512 + n] = acc[i][j][r];
      }
}

// ---------------- host ----------------
extern "C" void kernel_launch(void* const* d_in, const int* in_sizes, int n_in,
                              void* d_out, int out_size, void* d_ws, size_t ws_size,
                              hipStream_t stream) {
  const float* x     = (const float*)d_in[0];
  const float* W_ih0 = (const float*)d_in[1];
  const float* W_hh0 = (const float*)d_in[2];
  const float* b_ih0 = (const float*)d_in[3];
  const float* b_hh0 = (const float*)d_in[4];
  const float* W_ih1 = (const float*)d_in[5];
  const float* W_hh1 = (const float*)d_in[6];
  const float* b_ih1 = (const float*)d_in[7];
  const float* b_hh1 = (const float*)d_in[8];
  const float* W_fc  = (const float*)d_in[9];
  const float* b_fc  = (const float*)d_in[10];
  float* out = (float*)d_out;

  char* ws = (char*)d_ws;
  const size_t OFF_XBF = 0;               // [1024][64][256] bf16 = 33,554,432
  const size_t OFF_YBF = 33554432;        // [64][1024][512] bf16 = 67,108,864
  const size_t OFF_WFC = 100663296;       // 512*512 bf16 = 524,288
  const size_t OFF_H0  = 101187584;       // 2 * 64*512 bf16 = 131,072
  const size_t OFF_H1  = 101318656;       // 131,072
  const size_t OFF_BAR = 101449728;       // 64 slots * 64B = 4096
  const size_t OFF_TKT = 101453824;       // ticket, 256B

  u16* x_bf   = (u16*)(ws + OFF_XBF);
  u16* y_bf   = (u16*)(ws + OFF_YBF);
  u16* wfc_bf = (u16*)(ws + OFF_WFC);
  u16* h0buf  = (u16*)(ws + OFF_H0);
  u16* h1buf  = (u16*)(ws + OFF_H1);
  unsigned* slots = (unsigned*)(ws + OFF_BAR);
  int* ticket     = (int*)(ws + OFF_TKT);

  // zero h ping-pong buffers + barrier slots + ticket (contiguous)
  hipMemsetAsync(ws + OFF_H0, 0, 131072 * 2 + 4096 + 256, stream);

  // x: transpose+convert; W_fc: convert
  conv_x<<<16384, 256, 0, stream>>>(x, x_bf);
  conv_bf16<<<256, 256, 0, stream>>>(W_fc, wfc_bf, (O_ * H_) / 4);

  // whole recurrence in one persistent kernel; 1024 blocks launched, the 64
  // that land on XCD 0 become workers, the rest exit immediately.
  gru_persistent<<<1024, 256, 0, stream>>>(
      x_bf, W_ih0, W_hh0, b_ih0, b_hh0, W_ih1, W_hh1, b_ih1, b_hh1,
      h0buf, h1buf, y_bf, out + (size_t)B_ * S_ * O_, slots, ticket);

  // logits = Y @ Wfc^T + b_fc
  fc_gemm<<<2048, 256, 0, stream>>>(y_bf, wfc_bf, b_fc, out);
}

// Round 10
// 7058.183 us; speedup vs baseline: 2.2616x; 2.2616x over previous
//
#include <hip/hip_runtime.h>

// GRU 2-layer persistent-kernel design (Round 11).
// B=64, S=1024, I=256, H=512, O=512.
// - ONE persistent kernel runs the whole 1024-step recurrence.
// - 64 blocks x 256 threads (1 block/CU); blocks 0..31 layer0, 32..63 layer1.
// - wavefront pipelining: ONE grid barrier per step (1025 intervals).
// - weights as bf16 MFMA B-fragments in REGISTERS (loaded once).
// R11 = R7 (7.07ms verified: sc1 COALESCED publishes => L2 always clean;
// cached h reads; flat 64B-stride slot store/poll barrier) + RING-AMORTIZED
// ACQUIRE:
//   * R7 residual: 64 per-block fence(ACQUIRE,agent) L1+L2 invs EVERY step
//     (~4us/step, ~8 serializing per XCD L2). The inv is only needed because
//     depth-2 ping-pong reuses h addresses every 2 steps.
//   * R11: h ring of 32 slots per layer (slot = t mod 32). A reader's cached
//     slot-s line is re-touched only 32 steps later; ONE inv per 16 steps
//     guarantees >=1 (actually 2) invs inside every 32-step reuse window.
//   * Non-inv steps: barrier = sc1 store/poll ONLY (R4/R6-proven structure;
//     trailing __syncthreads is the compiler fence; waves issue in-order so
//     no load passes the poll branch).
//   * Invariants: L2 always clean (h/ybf/outh sc1) => inv never discards
//     data (R7-proven); slot lines are first-touched only AFTER their write
//     (lockstep barrier) => first fetch is fresh; skew <=1 << 32.
//   * NOT doing per-XCD leader hierarchies: both attempts (R5, R10) died at
//     harness level - treated as hang-prone, abandoned.

typedef unsigned short u16;
typedef unsigned long long u64;
typedef __attribute__((ext_vector_type(8))) short bf16x8;
typedef __attribute__((ext_vector_type(4))) float f32x4;

#define B_ 64
#define S_ 1024
#define I_ 256
#define H_ 512
#define O_ 512
#define NBLK 64
#define RING 32          // h ring depth (slots per layer)
#define INVP 16          // acquire-inv period; INVP <= RING/2 (margin 2x)

#define MFMA_(a, b, c) __builtin_amdgcn_mfma_f32_16x16x32_bf16((a), (b), (c), 0, 0, 0)

__device__ __forceinline__ u16 f2bf(float f) {
  union { float f; unsigned u; } v; v.f = f;
  unsigned r = v.u + 0x7fffu + ((v.u >> 16) & 1u);  // RNE
  return (u16)(r >> 16);
}

__device__ __forceinline__ float sigmoidf_(float x) {
  return 1.0f / (1.0f + __expf(-x));
}

__device__ __forceinline__ void store_sc1_u64(void* p, u64 v) {
  __hip_atomic_store((u64*)p, v, __ATOMIC_RELAXED, __HIP_MEMORY_SCOPE_AGENT);
}

// Grid barrier (R11): R7's arrival/poll; acquire fence only on inv steps.
// slots: 64 entries, 64B stride; slot[b] = last target block b reached.
// __syncthreads drains vmcnt(0): all sc1 publish stores ACKed at L3 before
// the arrival store issues. doInv: one fence(ACQUIRE)=L1+L2 inv per INVP
// steps (ring makes per-step inv unnecessary).
__device__ __forceinline__ void grid_bar(unsigned* slots, unsigned target,
                                         bool doInv) {
  __syncthreads();
  if (threadIdx.x < 64) {
    if (threadIdx.x == 0) {
      __hip_atomic_store(slots + ((unsigned)blockIdx.x << 4), target,
                         __ATOMIC_RELAXED, __HIP_MEMORY_SCOPE_AGENT);
    }
    const unsigned* myslot = slots + ((unsigned)threadIdx.x << 4);
    unsigned v;
    do {
      v = __hip_atomic_load(myslot, __ATOMIC_RELAXED, __HIP_MEMORY_SCOPE_AGENT);
      if (v < target) __builtin_amdgcn_s_sleep(2);
    } while (v < target);
    if (doInv && threadIdx.x == 0)
      __builtin_amdgcn_fence(__ATOMIC_ACQUIRE, "agent");  // waitcnt + buffer_inv
  }
  __syncthreads();
}

// One layer's persistent loop. NK = K/(32*4) per wave. LAYER selects routing.
// xin: LAYER0 -> x_bf [t][b][c]; LAYER1 -> h0 RING base.
// hring: own layer's h ring base [RING][64*512] bf16.
template<int NK, int LAYER>
__device__ void layer_run(
    const u16* __restrict__ xin,
    const float* __restrict__ Wih, const float* __restrict__ Whh,
    const float* __restrict__ bih, const float* __restrict__ bhh,
    u16* __restrict__ hring,            // ring [RING][64*512] bf16
    u16* __restrict__ ybf,              // LAYER1: [b][t][u] bf16
    float* __restrict__ outh,           // final hidden f32 [64*512]
    float (*dump)[4][4][256], float* hst, float (*bias_s)[16], unsigned* slots)
{
  const int tid = threadIdx.x;
  const int wave = tid >> 6, lane = tid & 63, lm = lane & 15, quad = lane >> 4;
  const int U0 = (blockIdx.x & 31) << 4;       // this block's 16 hidden units
  const int Kx = (LAYER == 0) ? I_ : H_;       // boundary between gi and gh input
  const int KW = NK * 32;                      // K-slice per wave
  const int wbase = wave * KW;

  if (tid < 16) {
    bias_s[0][tid] = bih[U0 + tid] + bhh[U0 + tid];                  // r
    bias_s[1][tid] = bih[H_ + U0 + tid] + bhh[H_ + U0 + tid];        // z
    bias_s[2][tid] = bih[2 * H_ + U0 + tid];                         // n (x part)
    bias_s[3][tid] = bhh[2 * H_ + U0 + tid];                         // n (h part)
  }
  #pragma unroll
  for (int j = 0; j < 4; ++j) hst[tid + j * 256] = 0.f;

  // ---- load B fragments once: f32 weights -> bf16 regs ----
  bf16x8 Bfr[3][NK];
  int aoffb[NK], astr16[NK];
  bool insel[NK], isx[NK];
  #pragma unroll
  for (int ks = 0; ks < NK; ++ks) {
    const int kb = wbase + ks * 32;
    const bool xr = (kb < Kx);
    insel[ks] = xr; isx[ks] = xr;
    const int col = (xr ? kb : kb - Kx) + quad * 8;
    const int stride = xr ? ((LAYER == 0) ? I_ : H_) : H_;
    aoffb[ks] = lm * stride + col;
    astr16[ks] = stride << 4;
    #pragma unroll
    for (int g = 0; g < 3; ++g) {
      const int row = g * H_ + U0 + lm;
      const float* src = xr ? (Wih + (size_t)row * Kx + kb + quad * 8)
                            : (Whh + (size_t)row * H_ + (kb - Kx) + quad * 8);
      float4 lo = *(const float4*)src;
      float4 hi = *(const float4*)(src + 4);
      bf16x8 v;
      v[0] = (short)f2bf(lo.x); v[1] = (short)f2bf(lo.y);
      v[2] = (short)f2bf(lo.z); v[3] = (short)f2bf(lo.w);
      v[4] = (short)f2bf(hi.x); v[5] = (short)f2bf(hi.y);
      v[6] = (short)f2bf(hi.z); v[7] = (short)f2bf(hi.w);
      Bfr[g][ks] = v;
    }
  }
  __syncthreads();

  // ---- time loop: 1025 barrier intervals ----
  for (unsigned i = 0; i <= S_; ++i) {
    const bool active = (LAYER == 0) ? (i < S_) : (i >= 1);
    if (active) {
      const int t = (LAYER == 0) ? (int)i : (int)i - 1;
      // LAYER0 input: x [t][b][c]. LAYER1 input: h0 ring slot t.
      const u16* ain = (LAYER == 0)
          ? (xin + (size_t)t * (B_ * I_))
          : (xin + (size_t)(t & (RING - 1)) * (B_ * H_));
      const u16* aself = hring + (size_t)((t - 1) & (RING - 1)) * (B_ * H_);

      // ---- PHASE 1: issue ALL A-fragment loads (plain cached; L2-dedup) ----
      bf16x8 Afr[NK][4];
      #pragma unroll
      for (int ks = 0; ks < NK; ++ks) {
        const u16* p = (insel[ks] ? ain : aself) + aoffb[ks];
        Afr[ks][0] = *(const bf16x8*)(p);
        Afr[ks][1] = *(const bf16x8*)(p + astr16[ks]);
        Afr[ks][2] = *(const bf16x8*)(p + 2 * astr16[ks]);
        Afr[ks][3] = *(const bf16x8*)(p + 3 * astr16[ks]);
      }

      // ---- PHASE 2: all MFMAs (register-only) ----
      f32x4 aR[4] = {}, aZ[4] = {}, aNx[4] = {}, aNh[4] = {};
      #pragma unroll
      for (int ks = 0; ks < NK; ++ks) {
        aR[0] = MFMA_(Afr[ks][0], Bfr[0][ks], aR[0]);
        aR[1] = MFMA_(Afr[ks][1], Bfr[0][ks], aR[1]);
        aR[2] = MFMA_(Afr[ks][2], Bfr[0][ks], aR[2]);
        aR[3] = MFMA_(Afr[ks][3], Bfr[0][ks], aR[3]);
        aZ[0] = MFMA_(Afr[ks][0], Bfr[1][ks], aZ[0]);
        aZ[1] = MFMA_(Afr[ks][1], Bfr[1][ks], aZ[1]);
        aZ[2] = MFMA_(Afr[ks][2], Bfr[1][ks], aZ[2]);
        aZ[3] = MFMA_(Afr[ks][3], Bfr[1][ks], aZ[3]);
        if (isx[ks]) {
          aNx[0] = MFMA_(Afr[ks][0], Bfr[2][ks], aNx[0]);
          aNx[1] = MFMA_(Afr[ks][1], Bfr[2][ks], aNx[1]);
          aNx[2] = MFMA_(Afr[ks][2], Bfr[2][ks], aNx[2]);
          aNx[3] = MFMA_(Afr[ks][3], Bfr[2][ks], aNx[3]);
        } else {
          aNh[0] = MFMA_(Afr[ks][0], Bfr[2][ks], aNh[0]);
          aNh[1] = MFMA_(Afr[ks][1], Bfr[2][ks], aNh[1]);
          aNh[2] = MFMA_(Afr[ks][2], Bfr[2][ks], aNh[2]);
          aNh[3] = MFMA_(Afr[ks][3], Bfr[2][ks], aNh[3]);
        }
      }

      // dump partials to LDS
      #pragma unroll
      for (int mt = 0; mt < 4; ++mt) {
        *(f32x4*)&dump[wave][0][mt][lane << 2] = aR[mt];
        *(f32x4*)&dump[wave][1][mt][lane << 2] = aZ[mt];
        *(f32x4*)&dump[wave][2][mt][lane << 2] = aNx[mt];
        *(f32x4*)&dump[wave][3][mt][lane << 2] = aNh[mt];
      }
      __syncthreads();

      // reduce + gate math + publish (R7-exact): thread owns 4 CONSECUTIVE
      // units of one batch row -> one coalesced 8B sc1 publish.
      // (R8 lesson: the reduce-phase LDS bank conflicts of this mapping are
      // NOT on the critical path; do not "fix" them at the cost of an extra
      // sync/pack phase.)
      u16* hpub = hring + (size_t)(t & (RING - 1)) * (B_ * H_);
      {
        const int m = tid >> 2, u4 = (tid & 3) << 2;
        const int mt = m >> 4;
        u16 hb4[4];
        float hf4[4];
        #pragma unroll
        for (int j = 0; j < 4; ++j) {
          const int u = u4 + j;
          const int idx = ((m & 12) << 4) | (u << 2) | (m & 3);
          float r = 0.f, z = 0.f, nx = 0.f, nh = 0.f;
          #pragma unroll
          for (int w = 0; w < 4; ++w) {
            r  += dump[w][0][mt][idx];
            z  += dump[w][1][mt][idx];
            nx += dump[w][2][mt][idx];
            nh += dump[w][3][mt][idx];
          }
          r = sigmoidf_(r + bias_s[0][u]);
          z = sigmoidf_(z + bias_s[1][u]);
          const float nn = tanhf(nx + bias_s[2][u] + r * (nh + bias_s[3][u]));
          const float hp = hst[(m << 4) | u];
          const float hn = (1.f - z) * nn + z * hp;
          hst[(m << 4) | u] = hn;
          hb4[j] = f2bf(hn);
          hf4[j] = hn;
        }
        const u64 pk = (u64)hb4[0] | ((u64)hb4[1] << 16) |
                       ((u64)hb4[2] << 32) | ((u64)hb4[3] << 48);
        store_sc1_u64(hpub + m * H_ + U0 + u4, pk);           // h publish (8B)
        if (LAYER == 1)
          store_sc1_u64(ybf + ((size_t)m * S_ + t) * H_ + U0 + u4, pk);
        if (t == S_ - 1) {
          union { float f[2]; u64 u; } o0, o1;
          o0.f[0] = hf4[0]; o0.f[1] = hf4[1];
          o1.f[0] = hf4[2]; o1.f[1] = hf4[3];
          store_sc1_u64(outh + m * H_ + U0 + u4, o0.u);
          store_sc1_u64(outh + m * H_ + U0 + u4 + 2, o1.u);
        }
      }
    }
    // acquire-inv only every INVP steps (ring reuse distance RING = 2*INVP)
    grid_bar(slots, i + 1, (i & (INVP - 1)) == (INVP - 1));
  }
}

__global__ __launch_bounds__(256, 1) void gru_persistent(
    const u16* __restrict__ x_bf,
    const float* __restrict__ Wih0, const float* __restrict__ Whh0,
    const float* __restrict__ bih0, const float* __restrict__ bhh0,
    const float* __restrict__ Wih1, const float* __restrict__ Whh1,
    const float* __restrict__ bih1, const float* __restrict__ bhh1,
    u16* __restrict__ h0ring, u16* __restrict__ h1ring,
    u16* __restrict__ ybf, float* __restrict__ outh, unsigned* slots)
{
  __shared__ float dump[4][4][4][256];   // 64 KB
  __shared__ float hst[1024];            // 4 KB fp32 h state (this block's slice)
  __shared__ float bias_s[4][16];
  if (blockIdx.x < 32)
    layer_run<6, 0>(x_bf, Wih0, Whh0, bih0, bhh0, h0ring, (u16*)nullptr,
                    outh, dump, hst, bias_s, slots);
  else
    layer_run<8, 1>(h0ring, Wih1, Whh1, bih1, bhh1, h1ring, ybf,
                    outh + B_ * H_, dump, hst, bias_s, slots);
}

// ---------------- x transpose+convert: [b][t][c] f32 -> [t][b][c] bf16 ----------------
__global__ void conv_x(const float* __restrict__ src, u16* __restrict__ dst) {
  const int idx = blockIdx.x * 256 + threadIdx.x;   // 64*1024*64 quads
  const int c4 = idx & 63, tt = (idx >> 6) & 1023, b = idx >> 16;
  float4 v = *(const float4*)(src + (((size_t)(b << 10) | tt) << 8) + (c4 << 2));
  ushort4 o;
  o.x = f2bf(v.x); o.y = f2bf(v.y); o.z = f2bf(v.z); o.w = f2bf(v.w);
  *(ushort4*)(dst + (((size_t)(tt << 6) | b) << 8) + (c4 << 2)) = o;
}

// ---------------- generic f32 -> bf16 ----------------
__global__ void conv_bf16(const float* __restrict__ src, u16* __restrict__ dst, int n4) {
  int i = blockIdx.x * blockDim.x + threadIdx.x;
  int stride = gridDim.x * blockDim.x;
  for (; i < n4; i += stride) {
    float4 v = ((const float4*)src)[i];
    ushort4 o;
    o.x = f2bf(v.x); o.y = f2bf(v.y); o.z = f2bf(v.z); o.w = f2bf(v.w);
    ((ushort4*)dst)[i] = o;
  }
}

// ---------------- final FC: C[65536,512] = Y @ Wfc^T + b (verified R1) ----------------
__global__ __launch_bounds__(256) void fc_gemm(
    const u16* __restrict__ A, const u16* __restrict__ Bm,
    const float* __restrict__ bias, float* __restrict__ C)
{
  const int bid = blockIdx.x;
  const int bm = bid >> 2, bn = bid & 3;
  const int wave = threadIdx.x >> 6, lane = threadIdx.x & 63;
  const int wm = wave >> 1, wn = wave & 1;
  const int M0 = bm * 128 + wm * 64;
  const int N0 = bn * 128 + wn * 64;
  const int lm = lane & 15, quad = lane >> 4;

  f32x4 acc[4][4];
  #pragma unroll
  for (int j = 0; j < 4; ++j) {
    float bv = bias[N0 + j * 16 + lm];
    #pragma unroll
    for (int i = 0; i < 4; ++i) acc[i][j] = (f32x4){bv, bv, bv, bv};
  }

  const u16* a0 = A + (size_t)(M0 + lm) * 512 + quad * 8;
  const u16* b0 = Bm + (size_t)(N0 + lm) * 512 + quad * 8;
  for (int ks = 0; ks < 512; ks += 32) {
    bf16x8 af[4], bfr[4];
    #pragma unroll
    for (int i = 0; i < 4; ++i) af[i]  = *(const bf16x8*)(a0 + (size_t)i * 16 * 512 + ks);
    #pragma unroll
    for (int j = 0; j < 4; ++j) bfr[j] = *(const bf16x8*)(b0 + (size_t)j * 16 * 512 + ks);
    #pragma unroll
    for (int i = 0; i < 4; ++i)
      #pragma unroll
      for (int j = 0; j < 4; ++j)
        acc[i][j] = MFMA_(af[i], bfr[j], acc[i][j]);
  }

  #pragma unroll
  for (int i = 0; i < 4; ++i)
    #pragma unroll
    for (int j = 0; j < 4; ++j)
      #pragma unroll
      for (int r = 0; r < 4; ++r) {
        const int m = M0 + i * 16 + quad * 4 + r;
        const int n = N0 + j * 16 + lm;
        C[(size_t)m * 512 + n] = acc[i][j][r];
      }
}

// ---------------- host ----------------
extern "C" void kernel_launch(void* const* d_in, const int* in_sizes, int n_in,
                              void* d_out, int out_size, void* d_ws, size_t ws_size,
                              hipStream_t stream) {
  const float* x     = (const float*)d_in[0];
  const float* W_ih0 = (const float*)d_in[1];
  const float* W_hh0 = (const float*)d_in[2];
  const float* b_ih0 = (const float*)d_in[3];
  const float* b_hh0 = (const float*)d_in[4];
  const float* W_ih1 = (const float*)d_in[5];
  const float* W_hh1 = (const float*)d_in[6];
  const float* b_ih1 = (const float*)d_in[7];
  const float* b_hh1 = (const float*)d_in[8];
  const float* W_fc  = (const float*)d_in[9];
  const float* b_fc  = (const float*)d_in[10];
  float* out = (float*)d_out;

  char* ws = (char*)d_ws;
  const size_t OFF_XBF = 0;               // [1024][64][256] bf16 = 33,554,432
  const size_t OFF_YBF = 33554432;        // [64][1024][512] bf16 = 67,108,864
  const size_t OFF_WFC = 100663296;       // 512*512 bf16 = 524,288
  const size_t OFF_H0  = 101187584;       // RING * 64*512 bf16 = 2,097,152
  const size_t OFF_H1  = 103284736;       // 2,097,152
  const size_t OFF_BAR = 105381888;       // 64 slots * 64B = 4096

  u16* x_bf   = (u16*)(ws + OFF_XBF);
  u16* y_bf   = (u16*)(ws + OFF_YBF);
  u16* wfc_bf = (u16*)(ws + OFF_WFC);
  u16* h0ring = (u16*)(ws + OFF_H0);
  u16* h1ring = (u16*)(ws + OFF_H1);
  unsigned* slots = (unsigned*)(ws + OFF_BAR);

  // zero both h rings + barrier slots (contiguous region)
  hipMemsetAsync(ws + OFF_H0, 0, 2097152 * 2 + 4096, stream);

  // x: transpose+convert; W_fc: convert
  conv_x<<<16384, 256, 0, stream>>>(x, x_bf);
  conv_bf16<<<256, 256, 0, stream>>>(W_fc, wfc_bf, (O_ * H_) / 4);

  // whole recurrence in one persistent kernel
  gru_persistent<<<NBLK, 256, 0, stream>>>(
      x_bf, W_ih0, W_hh0, b_ih0, b_hh0, W_ih1, W_hh1, b_ih1, b_hh1,
      h0ring, h1ring, y_bf, out + (size_t)B_ * S_ * O_, slots);

  // logits = Y @ Wfc^T + b_fc
  fc_gemm<<<2048, 256, 0, stream>>>(y_bf, wfc_bf, b_fc, out);
}